// Round 1
// baseline (2198.736 us; speedup 1.0000x reference)
//
#include <hip/hip_runtime.h>
#include <math.h>

#define L 9216
#define HH 96
#define WW 96
#define CC 256
#define CR 64
#define NB 8
#define NCLUST 128
#define WIN 144
#define NK 64   // L/WIN

// ---------------- K1: conv3x3 (pad=1) -> x_embed[b][l][64] ----------------
__global__ __launch_bounds__(256) void k_conv3(const float* __restrict__ in,
                                               const float* __restrict__ wm,
                                               const float* __restrict__ bm,
                                               float* __restrict__ xe) {
  int h = blockIdx.x, b = blockIdx.y;
  __shared__ float in_s[16 * 300];   // [ic][3][100] cols 0..97 used
  __shared__ float w_s[144 * 66];    // [r=ic*9+tap][oc] padded
  int t = threadIdx.x;
  int ocg = t >> 4, wg = t & 15;
  int oc0 = ocg * 4, w0 = wg * 6;
  float acc[4][6];
  for (int j = 0; j < 4; ++j) {
    float bv = bm[oc0 + j];
    for (int i = 0; i < 6; ++i) acc[j][i] = bv;
  }
  const float* inb = in + (size_t)b * CC * L;
  for (int icc = 0; icc < 16; ++icc) {
    int ic0 = icc * 16;
    for (int e = t; e < 16 * 3 * 98; e += 256) {
      int ic = e / 294, rem = e % 294;
      int r = rem / 98, col = rem % 98;
      int gr = h + r - 1, gc = col - 1;
      float v = 0.f;
      if (gr >= 0 && gr < HH && gc >= 0 && gc < WW)
        v = inb[(size_t)(ic0 + ic) * L + gr * WW + gc];
      in_s[ic * 300 + r * 100 + col] = v;
    }
    for (int e = t; e < 9216; e += 256) {
      int oc = e / 144, r = e % 144;
      w_s[r * 66 + oc] = wm[(size_t)oc * 2304 + (size_t)ic0 * 9 + r];
    }
    __syncthreads();
    for (int ic = 0; ic < 16; ++ic) {
      for (int kh = 0; kh < 3; ++kh) {
        float iv[8];
#pragma unroll
        for (int i = 0; i < 8; ++i) iv[i] = in_s[ic * 300 + kh * 100 + w0 + i];
#pragma unroll
        for (int kw = 0; kw < 3; ++kw) {
          float wv[4];
#pragma unroll
          for (int j = 0; j < 4; ++j)
            wv[j] = w_s[(ic * 9 + kh * 3 + kw) * 66 + oc0 + j];
#pragma unroll
          for (int j = 0; j < 4; ++j)
#pragma unroll
            for (int i = 0; i < 6; ++i) acc[j][i] += wv[j] * iv[i + kw];
        }
      }
    }
    __syncthreads();
  }
  for (int i = 0; i < 6; ++i) {
    int l = h * WW + w0 + i;
    float4 o;
    o.x = acc[0][i]; o.y = acc[1][i]; o.z = acc[2][i]; o.w = acc[3][i];
    *(float4*)&xe[((size_t)b * L + l) * CR + oc0] = o;
  }
}

// ---------------- K2: conv1x1 -> y_embed[b][l][256] ----------------
__global__ __launch_bounds__(256) void k_conv1(const float* __restrict__ in,
                                               const float* __restrict__ wa,
                                               const float* __restrict__ ba,
                                               float* __restrict__ ye) {
  int lt = blockIdx.x, ot = blockIdx.y, b = blockIdx.z;
  int l0 = lt * 64, ocb = ot * 64;
  __shared__ float in_s[32 * 64];
  __shared__ float w_s[32 * 66];
  int t = threadIdx.x;
  int ocg = t & 15, pg = t >> 4;
  int oc0 = ocg * 4, px0 = pg * 4;
  float acc[4][4];  // [px][oc]
  for (int p = 0; p < 4; ++p)
    for (int j = 0; j < 4; ++j) acc[p][j] = ba[ocb + oc0 + j];
  const float* inb = in + (size_t)b * CC * L;
  for (int icc = 0; icc < 8; ++icc) {
    int ic0 = icc * 32;
    for (int e = t; e < 2048; e += 256) {
      int ic = e >> 6, px = e & 63;
      in_s[ic * 64 + px] = inb[(size_t)(ic0 + ic) * L + l0 + px];
    }
    for (int e = t; e < 2048; e += 256) {
      int oc = e >> 5, ic = e & 31;
      w_s[ic * 66 + oc] = wa[(size_t)(ocb + oc) * CC + ic0 + ic];
    }
    __syncthreads();
    for (int ic = 0; ic < 32; ++ic) {
      float w0v = w_s[ic * 66 + oc0 + 0];
      float w1v = w_s[ic * 66 + oc0 + 1];
      float w2v = w_s[ic * 66 + oc0 + 2];
      float w3v = w_s[ic * 66 + oc0 + 3];
      float4 xv = *(float4*)&in_s[ic * 64 + px0];
      acc[0][0] += xv.x * w0v; acc[0][1] += xv.x * w1v; acc[0][2] += xv.x * w2v; acc[0][3] += xv.x * w3v;
      acc[1][0] += xv.y * w0v; acc[1][1] += xv.y * w1v; acc[1][2] += xv.y * w2v; acc[1][3] += xv.y * w3v;
      acc[2][0] += xv.z * w0v; acc[2][1] += xv.z * w1v; acc[2][2] += xv.z * w2v; acc[2][3] += xv.z * w3v;
      acc[3][0] += xv.w * w0v; acc[3][1] += xv.w * w1v; acc[3][2] += xv.w * w2v; acc[3][3] += xv.w * w3v;
    }
    __syncthreads();
  }
  for (int p = 0; p < 4; ++p) {
    float4 o;
    o.x = acc[p][0]; o.y = acc[p][1]; o.z = acc[p][2]; o.w = acc[p][3];
    *(float4*)&ye[((size_t)b * L + l0 + px0 + p) * CC + ocb + oc0] = o;
  }
}

// ---------------- K3: buckets = argmax_c(x . mean_c) ----------------
__global__ __launch_bounds__(256) void k_bucket(const float* __restrict__ xe,
                                                const float* __restrict__ means,
                                                int* __restrict__ buckets) {
  int lt = blockIdx.x, b = blockIdx.y;
  int l0 = lt * 32;
  __shared__ float x_s[32 * 65];
  __shared__ float m_s[128 * 65];
  __shared__ float bv_s[32 * 8];
  __shared__ int bi_s[32 * 8];
  int t = threadIdx.x;
  for (int e = t; e < 2048; e += 256) {
    int px = e >> 6, d = e & 63;
    x_s[px * 65 + d] = xe[((size_t)b * L + l0) * 64 + e];
  }
  for (int e = t; e < 8192; e += 256) {
    int c = e >> 6, d = e & 63;
    m_s[c * 65 + d] = means[e];
  }
  __syncthreads();
  int px = t >> 3, cg = t & 7;
  float best = -1e30f;
  int bidx = 0;
  const float* xr = &x_s[px * 65];
  for (int cc = 0; cc < 16; ++cc) {
    int c = cg + 8 * cc;
    const float* mr = &m_s[c * 65];
    float d = 0.f;
#pragma unroll
    for (int dd = 0; dd < 64; ++dd) d += xr[dd] * mr[dd];
    if (d > best || (d == best && c < bidx)) { best = d; bidx = c; }
  }
  bv_s[px * 8 + cg] = best;
  bi_s[px * 8 + cg] = bidx;
  __syncthreads();
  if (cg == 0) {
    float bb = bv_s[px * 8];
    int bbi = bi_s[px * 8];
    for (int g = 1; g < 8; ++g) {
      float v = bv_s[px * 8 + g];
      int vi = bi_s[px * 8 + g];
      if (v > bb || (v == bb && vi < bbi)) { bb = v; bbi = vi; }
    }
    buckets[b * L + l0 + px] = bbi;
  }
}

// ---------------- K4: stable counting sort -> sidx[b][i] = original l ----------------
__global__ __launch_bounds__(128) void k_sort(const int* __restrict__ buckets,
                                              int* __restrict__ sidx) {
  int b = blockIdx.x, t = threadIdx.x;
  __shared__ int bl_s[L];
  __shared__ int hist[128];
  const int* bk = buckets + b * L;
  for (int l = t; l < L; l += 128) bl_s[l] = bk[l];
  __syncthreads();
  int cnt = 0;
  for (int l = 0; l < L; ++l) cnt += (bl_s[l] == t);
  hist[t] = cnt;
  __syncthreads();
  if (t == 0) {
    int s = 0;
    for (int i = 0; i < 128; ++i) { int c = hist[i]; hist[i] = s; s += c; }
  }
  __syncthreads();
  int pos = hist[t];
  for (int l = 0; l < L; ++l)
    if (bl_s[l] == t) sidx[b * L + pos++] = l;
}

// ---------------- K5: gather + normalize ----------------
__global__ __launch_bounds__(256) void k_gather(const float* __restrict__ xe,
                                                const float* __restrict__ ye,
                                                const int* __restrict__ sidx,
                                                float* __restrict__ xmn,
                                                float* __restrict__ ys,
                                                float* __restrict__ norms) {
  int it = blockIdx.x, b = blockIdx.y;
  int i0 = it * 64;
  __shared__ float x_s[64 * 65];
  __shared__ int idx_s[64];
  __shared__ float scale_s[64];
  int t = threadIdx.x;
  if (t < 64) idx_s[t] = sidx[b * L + i0 + t];
  __syncthreads();
  for (int e = t; e < 4096; e += 256) {
    int i = e >> 6, d = e & 63;
    x_s[i * 65 + d] = xe[((size_t)b * L + idx_s[i]) * 64 + d];
  }
  __syncthreads();
  if (t < 64) {
    float s = 0.f;
    const float* xr = &x_s[t * 65];
#pragma unroll
    for (int d = 0; d < 64; ++d) s += xr[d] * xr[d];
    float n = fmaxf(sqrtf(s), 5e-5f);
    norms[b * L + i0 + t] = n;
    scale_s[t] = 1.0f / n;
  }
  __syncthreads();
  for (int e = t; e < 4096; e += 256) {
    int i = e >> 6, d = e & 63;
    xmn[((size_t)b * L + i0) * 64 + e] = x_s[i * 65 + d] * scale_s[i];
  }
  for (int e = t; e < 64 * 256; e += 256) {
    int i = e >> 8, d = e & 255;
    ys[((size_t)b * L + i0) * 256 + e] = ye[((size_t)b * L + idx_s[i]) * 256 + d];
  }
}

// ---------------- K6: block-local attention ----------------
__global__ __launch_bounds__(256) void k_attn(const float* __restrict__ xmn,
                                              const float* __restrict__ ys,
                                              const float* __restrict__ norms,
                                              const int* __restrict__ sidx,
                                              float* __restrict__ retb) {
  int qc = blockIdx.x;   // 0..2 (48 queries each)
  int k = blockIdx.y;    // 0..63
  int b = blockIdx.z;
  __shared__ float q_s[48 * 64];
  __shared__ float kv_s[4096];       // K chunks: [48][68]; V chunks: [16][256]
  __shared__ float raw_s[48 * 440];  // scores, padded stride
  __shared__ float qn_s[48];
  __shared__ float red_s[48 * 4];
  __shared__ float rmax_s[48];
  __shared__ float rscale_s[48];
  int t = threadIdx.x;
  int kbase = k * WIN;
  int q0 = qc * 48;
  size_t qgb = ((size_t)b * L + kbase + q0) * 64;
  for (int e = t; e < 768; e += 256)
    *(float4*)&q_s[e * 4] = *(const float4*)&xmn[qgb + (size_t)e * 4];
  if (t < 48) qn_s[t] = norms[b * L + kbase + q0 + t];

  // ---- phase 1: raw scores ----
  int qt = t >> 4, kt = t & 15;
  int qi0 = qt * 3, kj0 = kt * 3;
  for (int kc = 0; kc < 9; ++kc) {
    int rg = kc / 3;
    int kk = (rg == 0) ? k : (rg == 1) ? ((k + 63) & 63) : ((k + 1) & 63);
    size_t kgb = ((size_t)b * L + kk * WIN + (kc % 3) * 48) * 64;
    for (int e = t; e < 768; e += 256) {
      int kj = e >> 4, d4 = e & 15;
      *(float4*)&kv_s[kj * 68 + d4 * 4] = *(const float4*)&xmn[kgb + (size_t)e * 4];
    }
    __syncthreads();
    float a[3][3] = {{0.f}};
    for (int dd = 0; dd < 64; dd += 4) {
      float4 qv0 = *(float4*)&q_s[(qi0 + 0) * 64 + dd];
      float4 qv1 = *(float4*)&q_s[(qi0 + 1) * 64 + dd];
      float4 qv2 = *(float4*)&q_s[(qi0 + 2) * 64 + dd];
      float4 kv0 = *(float4*)&kv_s[(kj0 + 0) * 68 + dd];
      float4 kv1 = *(float4*)&kv_s[(kj0 + 1) * 68 + dd];
      float4 kv2 = *(float4*)&kv_s[(kj0 + 2) * 68 + dd];
      a[0][0] += qv0.x * kv0.x + qv0.y * kv0.y + qv0.z * kv0.z + qv0.w * kv0.w;
      a[0][1] += qv0.x * kv1.x + qv0.y * kv1.y + qv0.z * kv1.z + qv0.w * kv1.w;
      a[0][2] += qv0.x * kv2.x + qv0.y * kv2.y + qv0.z * kv2.z + qv0.w * kv2.w;
      a[1][0] += qv1.x * kv0.x + qv1.y * kv0.y + qv1.z * kv0.z + qv1.w * kv0.w;
      a[1][1] += qv1.x * kv1.x + qv1.y * kv1.y + qv1.z * kv1.z + qv1.w * kv1.w;
      a[1][2] += qv1.x * kv2.x + qv1.y * kv2.y + qv1.z * kv2.z + qv1.w * kv2.w;
      a[2][0] += qv2.x * kv0.x + qv2.y * kv0.y + qv2.z * kv0.z + qv2.w * kv0.w;
      a[2][1] += qv2.x * kv1.x + qv2.y * kv1.y + qv2.z * kv1.z + qv2.w * kv1.w;
      a[2][2] += qv2.x * kv2.x + qv2.y * kv2.y + qv2.z * kv2.z + qv2.w * kv2.w;
    }
#pragma unroll
    for (int ii = 0; ii < 3; ++ii)
#pragma unroll
      for (int jj = 0; jj < 3; ++jj)
        raw_s[(qi0 + ii) * 440 + kc * 48 + kj0 + jj] = a[ii][jj] * qn_s[qi0 + ii];
    __syncthreads();
  }

  // ---- phase 2: softmax (max, exp, sum) ----
  if (t < 192) {
    int row = t >> 2, sub = t & 3;
    float m = -1e30f;
    for (int j = sub * 108; j < sub * 108 + 108; ++j)
      m = fmaxf(m, raw_s[row * 440 + j]);
    red_s[row * 4 + sub] = m;
  }
  __syncthreads();
  if (t < 48)
    rmax_s[t] = fmaxf(fmaxf(red_s[t * 4], red_s[t * 4 + 1]),
                      fmaxf(red_s[t * 4 + 2], red_s[t * 4 + 3]));
  __syncthreads();
  if (t < 192) {
    int row = t >> 2, sub = t & 3;
    float m = rmax_s[row];
    float s = 0.f;
    for (int j = sub * 108; j < sub * 108 + 108; ++j) {
      float p = expf(raw_s[row * 440 + j] - m);
      raw_s[row * 440 + j] = p;
      s += p;
    }
    red_s[row * 4 + sub] = s;
  }
  __syncthreads();
  if (t < 48)
    rscale_s[t] = 1.0f / (red_s[t * 4] + red_s[t * 4 + 1] + red_s[t * 4 + 2] + red_s[t * 4 + 3]);
  __syncthreads();

  // ---- phase 3: ret = P . V ----
  int cg = t & 63, qg = t >> 6;
  int c0 = cg * 4;
  float acc[12][4];
#pragma unroll
  for (int s = 0; s < 12; ++s)
    for (int j = 0; j < 4; ++j) acc[s][j] = 0.f;
  for (int jc = 0; jc < 27; ++jc) {
    int j0 = jc * 16;
    int rg = j0 / 144, joff = j0 % 144;
    int kk = (rg == 0) ? k : (rg == 1) ? ((k + 63) & 63) : ((k + 1) & 63);
    size_t vbase = ((size_t)b * L + kk * WIN + joff) * 256;
    for (int e = t; e < 1024; e += 256) {
      int jj = e >> 6, d4 = e & 63;
      *(float4*)&kv_s[jj * 256 + d4 * 4] = *(const float4*)&ys[vbase + (size_t)jj * 256 + d4 * 4];
    }
    __syncthreads();
#pragma unroll
    for (int jq = 0; jq < 4; ++jq) {
      float4 v0 = *(float4*)&kv_s[(jq * 4 + 0) * 256 + c0];
      float4 v1 = *(float4*)&kv_s[(jq * 4 + 1) * 256 + c0];
      float4 v2 = *(float4*)&kv_s[(jq * 4 + 2) * 256 + c0];
      float4 v3 = *(float4*)&kv_s[(jq * 4 + 3) * 256 + c0];
#pragma unroll
      for (int s = 0; s < 12; ++s) {
        int qi = qg + s * 4;
        float4 p = *(float4*)&raw_s[qi * 440 + j0 + jq * 4];
        acc[s][0] += p.x * v0.x + p.y * v1.x + p.z * v2.x + p.w * v3.x;
        acc[s][1] += p.x * v0.y + p.y * v1.y + p.z * v2.y + p.w * v3.y;
        acc[s][2] += p.x * v0.z + p.y * v1.z + p.z * v2.z + p.w * v3.z;
        acc[s][3] += p.x * v0.w + p.y * v1.w + p.z * v2.w + p.w * v3.w;
      }
    }
    __syncthreads();
  }
#pragma unroll
  for (int s = 0; s < 12; ++s) {
    int qi = qg + s * 4;
    int l = sidx[b * L + kbase + q0 + qi];
    float sc = rscale_s[qi];
    float4 o;
    o.x = acc[s][0] * sc; o.y = acc[s][1] * sc;
    o.z = acc[s][2] * sc; o.w = acc[s][3] * sc;
    *(float4*)&retb[((size_t)b * L + l) * 256 + c0] = o;
  }
}

// ---------------- K7: transpose + residual ----------------
__global__ __launch_bounds__(256) void k_final(const float* __restrict__ in,
                                               const float* __restrict__ retb,
                                               float* __restrict__ out) {
  int lt = blockIdx.x, ct = blockIdx.y, b = blockIdx.z;
  int l0 = lt * 32, c0 = ct * 32;
  __shared__ float t_s[32][33];
  int t = threadIdx.x;
  for (int e = t; e < 1024; e += 256) {
    int i = e >> 5, j = e & 31;  // i: l, j: c
    t_s[i][j] = retb[((size_t)b * L + l0 + i) * 256 + c0 + j];
  }
  __syncthreads();
  for (int e = t; e < 1024; e += 256) {
    int ci = e >> 5, lj = e & 31;
    size_t o = ((size_t)b * CC + c0 + ci) * L + l0 + lj;
    out[o] = in[o] + 0.1f * t_s[lj][ci];
  }
}

extern "C" void kernel_launch(void* const* d_in, const int* in_sizes, int n_in,
                              void* d_out, int out_size, void* d_ws, size_t ws_size,
                              hipStream_t stream) {
  const float* input = (const float*)d_in[0];
  const float* wm = (const float*)d_in[1];
  const float* bm = (const float*)d_in[2];
  const float* wa = (const float*)d_in[3];
  const float* ba = (const float*)d_in[4];
  const float* means = (const float*)d_in[5];
  float* out = (float*)d_out;

  float* ws = (float*)d_ws;
  float* x_embed = ws;                            // 8*9216*64   = 4,718,592
  float* y_embed = x_embed + 4718592ull;          // 8*9216*256  = 18,874,368 (reused as ret)
  float* retb = y_embed;
  float* xmn = y_embed + 18874368ull;             // 4,718,592
  float* ys = xmn + 4718592ull;                   // 18,874,368
  float* norms = ys + 18874368ull;                // 73,728
  int* buckets = (int*)(norms + 73728ull);        // 73,728
  int* sidx = buckets + 73728;                    // 73,728

  k_conv3<<<dim3(96, 8), 256, 0, stream>>>(input, wm, bm, x_embed);
  k_conv1<<<dim3(144, 4, 8), 256, 0, stream>>>(input, wa, ba, y_embed);
  k_bucket<<<dim3(288, 8), 256, 0, stream>>>(x_embed, means, buckets);
  k_sort<<<dim3(8), 128, 0, stream>>>(buckets, sidx);
  k_gather<<<dim3(144, 8), 256, 0, stream>>>(x_embed, y_embed, sidx, xmn, ys, norms);
  k_attn<<<dim3(3, 64, 8), 256, 0, stream>>>(xmn, ys, norms, sidx, retb);
  k_final<<<dim3(288, 8, 8), 256, 0, stream>>>(input, retb, out);
}

// Round 3
// 1432.343 us; speedup vs baseline: 1.5351x; 1.5351x over previous
//
#include <hip/hip_runtime.h>
#include <math.h>

#define L 9216
#define HH 96
#define WW 96
#define CC 256
#define CR 64
#define NCLUST 128
#define WIN 144
#define NK 64   // L/WIN

typedef float f32x4 __attribute__((ext_vector_type(4)));
typedef short s8v __attribute__((ext_vector_type(8)));
typedef short s4v __attribute__((ext_vector_type(4)));

static __device__ __forceinline__ short f2bf(float x) {
  union { float f; unsigned u; } v; v.f = x;
  unsigned r = (v.u + 0x7FFF + ((v.u >> 16) & 1)) >> 16;
  return (short)r;
}

// ---------------- K1: conv3x3 (pad=1) -> x_embed[b][l][64] ----------------
__global__ __launch_bounds__(256) void k_conv3(const float* __restrict__ in,
                                               const float* __restrict__ wm,
                                               const float* __restrict__ bm,
                                               float* __restrict__ xe) {
  int h = blockIdx.x, b = blockIdx.y;
  __shared__ float in_s[16 * 300];
  __shared__ float w_s[144 * 66];
  int t = threadIdx.x;
  int ocg = t >> 4, wg = t & 15;
  int oc0 = ocg * 4, w0 = wg * 6;
  float acc[4][6];
  for (int j = 0; j < 4; ++j) {
    float bv = bm[oc0 + j];
    for (int i = 0; i < 6; ++i) acc[j][i] = bv;
  }
  const float* inb = in + (size_t)b * CC * L;
  for (int icc = 0; icc < 16; ++icc) {
    int ic0 = icc * 16;
    for (int e = t; e < 16 * 3 * 98; e += 256) {
      int ic = e / 294, rem = e % 294;
      int r = rem / 98, col = rem % 98;
      int gr = h + r - 1, gc = col - 1;
      float v = 0.f;
      if (gr >= 0 && gr < HH && gc >= 0 && gc < WW)
        v = inb[(size_t)(ic0 + ic) * L + gr * WW + gc];
      in_s[ic * 300 + r * 100 + col] = v;
    }
    for (int e = t; e < 9216; e += 256) {
      int oc = e / 144, r = e % 144;
      w_s[r * 66 + oc] = wm[(size_t)oc * 2304 + (size_t)ic0 * 9 + r];
    }
    __syncthreads();
    for (int ic = 0; ic < 16; ++ic) {
      for (int kh = 0; kh < 3; ++kh) {
        float iv[8];
#pragma unroll
        for (int i = 0; i < 8; ++i) iv[i] = in_s[ic * 300 + kh * 100 + w0 + i];
#pragma unroll
        for (int kw = 0; kw < 3; ++kw) {
          float wv[4];
#pragma unroll
          for (int j = 0; j < 4; ++j)
            wv[j] = w_s[(ic * 9 + kh * 3 + kw) * 66 + oc0 + j];
#pragma unroll
          for (int j = 0; j < 4; ++j)
#pragma unroll
            for (int i = 0; i < 6; ++i) acc[j][i] += wv[j] * iv[i + kw];
        }
      }
    }
    __syncthreads();
  }
  for (int i = 0; i < 6; ++i) {
    int l = h * WW + w0 + i;
    float4 o;
    o.x = acc[0][i]; o.y = acc[1][i]; o.z = acc[2][i]; o.w = acc[3][i];
    *(float4*)&xe[((size_t)b * L + l) * CR + oc0] = o;
  }
}

// ---------------- K2: conv1x1 -> y_embed[b][l][256] ----------------
__global__ __launch_bounds__(256) void k_conv1(const float* __restrict__ in,
                                               const float* __restrict__ wa,
                                               const float* __restrict__ ba,
                                               float* __restrict__ ye) {
  int lt = blockIdx.x, ot = blockIdx.y, b = blockIdx.z;
  int l0 = lt * 64, ocb = ot * 64;
  __shared__ float in_s[32 * 64];
  __shared__ float w_s[32 * 66];
  int t = threadIdx.x;
  int ocg = t & 15, pg = t >> 4;
  int oc0 = ocg * 4, px0 = pg * 4;
  float acc[4][4];
  for (int p = 0; p < 4; ++p)
    for (int j = 0; j < 4; ++j) acc[p][j] = ba[ocb + oc0 + j];
  const float* inb = in + (size_t)b * CC * L;
  for (int icc = 0; icc < 8; ++icc) {
    int ic0 = icc * 32;
    for (int e = t; e < 2048; e += 256) {
      int ic = e >> 6, px = e & 63;
      in_s[ic * 64 + px] = inb[(size_t)(ic0 + ic) * L + l0 + px];
    }
    for (int e = t; e < 2048; e += 256) {
      int oc = e >> 5, ic = e & 31;
      w_s[ic * 66 + oc] = wa[(size_t)(ocb + oc) * CC + ic0 + ic];
    }
    __syncthreads();
    for (int ic = 0; ic < 32; ++ic) {
      float w0v = w_s[ic * 66 + oc0 + 0];
      float w1v = w_s[ic * 66 + oc0 + 1];
      float w2v = w_s[ic * 66 + oc0 + 2];
      float w3v = w_s[ic * 66 + oc0 + 3];
      float4 xv = *(float4*)&in_s[ic * 64 + px0];
      acc[0][0] += xv.x * w0v; acc[0][1] += xv.x * w1v; acc[0][2] += xv.x * w2v; acc[0][3] += xv.x * w3v;
      acc[1][0] += xv.y * w0v; acc[1][1] += xv.y * w1v; acc[1][2] += xv.y * w2v; acc[1][3] += xv.y * w3v;
      acc[2][0] += xv.z * w0v; acc[2][1] += xv.z * w1v; acc[2][2] += xv.z * w2v; acc[2][3] += xv.z * w3v;
      acc[3][0] += xv.w * w0v; acc[3][1] += xv.w * w1v; acc[3][2] += xv.w * w2v; acc[3][3] += xv.w * w3v;
    }
    __syncthreads();
  }
  for (int p = 0; p < 4; ++p) {
    float4 o;
    o.x = acc[p][0]; o.y = acc[p][1]; o.z = acc[p][2]; o.w = acc[p][3];
    *(float4*)&ye[((size_t)b * L + l0 + px0 + p) * CC + ocb + oc0] = o;
  }
}

// ---------------- K3: buckets = argmax_c(x . mean_c) ----------------
__global__ __launch_bounds__(256) void k_bucket(const float* __restrict__ xe,
                                                const float* __restrict__ means,
                                                int* __restrict__ buckets) {
  int lt = blockIdx.x, b = blockIdx.y;
  int l0 = lt * 32;
  __shared__ float x_s[32 * 65];
  __shared__ float m_s[128 * 65];
  __shared__ float bv_s[32 * 8];
  __shared__ int bi_s[32 * 8];
  int t = threadIdx.x;
  for (int e = t; e < 2048; e += 256) {
    int px = e >> 6, d = e & 63;
    x_s[px * 65 + d] = xe[((size_t)b * L + l0) * 64 + e];
  }
  for (int e = t; e < 8192; e += 256) {
    int c = e >> 6, d = e & 63;
    m_s[c * 65 + d] = means[e];
  }
  __syncthreads();
  int px = t >> 3, cg = t & 7;
  float best = -1e30f;
  int bidx = 0;
  const float* xr = &x_s[px * 65];
  for (int cc = 0; cc < 16; ++cc) {
    int c = cg + 8 * cc;
    const float* mr = &m_s[c * 65];
    float d = 0.f;
#pragma unroll
    for (int dd = 0; dd < 64; ++dd) d += xr[dd] * mr[dd];
    if (d > best || (d == best && c < bidx)) { best = d; bidx = c; }
  }
  bv_s[px * 8 + cg] = best;
  bi_s[px * 8 + cg] = bidx;
  __syncthreads();
  if (cg == 0) {
    float bb = bv_s[px * 8];
    int bbi = bi_s[px * 8];
    for (int g = 1; g < 8; ++g) {
      float v = bv_s[px * 8 + g];
      int vi = bi_s[px * 8 + g];
      if (v > bb || (v == bb && vi < bbi)) { bb = v; bbi = vi; }
    }
    buckets[b * L + l0 + px] = bbi;
  }
}

// ---------------- K4: stable counting sort ----------------
__global__ __launch_bounds__(128) void k_sort(const int* __restrict__ buckets,
                                              int* __restrict__ sidx) {
  int b = blockIdx.x, t = threadIdx.x;
  __shared__ int bl_s[L];
  __shared__ int hist[128];
  const int* bk = buckets + b * L;
  for (int l = t; l < L; l += 128) bl_s[l] = bk[l];
  __syncthreads();
  int cnt = 0;
  for (int l = 0; l < L; ++l) cnt += (bl_s[l] == t);
  hist[t] = cnt;
  __syncthreads();
  if (t == 0) {
    int s = 0;
    for (int i = 0; i < 128; ++i) { int c = hist[i]; hist[i] = s; s += c; }
  }
  __syncthreads();
  int pos = hist[t];
  for (int l = 0; l < L; ++l)
    if (bl_s[l] == t) sidx[b * L + pos++] = l;
}

// ---------------- K5: gather + normalize -> xk (bf16 swizzled), yt (bf16 V^T tiles) ----------------
// yt layout per 16-key tile: [c (256)][k16 (16)], with k16-group swizzle:
//   stored slot = c*16 + (((k16>>2) ^ ((c>>2)&3))<<2 | (k16&3))
__global__ __launch_bounds__(256) void k_gather(const float* __restrict__ xe,
                                                const float* __restrict__ ye,
                                                const int* __restrict__ sidx,
                                                unsigned short* __restrict__ xk,
                                                unsigned short* __restrict__ yt,
                                                float* __restrict__ norms) {
  int it = blockIdx.x, b = blockIdx.y;
  int i0 = it * 64;
  __shared__ float x_s[64 * 65];
  __shared__ float y_s[16 * 260];
  __shared__ int idx_s[64];
  __shared__ float scale_s[64];
  int t = threadIdx.x;
  if (t < 64) idx_s[t] = sidx[b * L + i0 + t];
  __syncthreads();
  for (int e = t; e < 4096; e += 256) {
    int i = e >> 6, d = e & 63;
    x_s[i * 65 + d] = xe[((size_t)b * L + idx_s[i]) * 64 + d];
  }
  __syncthreads();
  if (t < 64) {
    float s = 0.f;
    const float* xr = &x_s[t * 65];
#pragma unroll
    for (int d = 0; d < 64; ++d) s += xr[d] * xr[d];
    float n = fmaxf(sqrtf(s), 5e-5f);
    norms[b * L + i0 + t] = n;
    scale_s[t] = 1.0f / n;
  }
  __syncthreads();
  // xk: normalized bf16, 16B blocks XOR-swizzled by (row&7)
  for (int e = t; e < 4096; e += 256) {
    int i = e >> 6, d = e & 63;
    int ig = i0 + i;
    int db = (((d >> 3) ^ (ig & 7)) << 3) | (d & 7);
    xk[((size_t)b * L + ig) * 64 + db] = (unsigned short)f2bf(x_s[i * 65 + d] * scale_s[i]);
  }
  // yt: V^T tiles via LDS transpose
  for (int tile = 0; tile < 4; ++tile) {
    for (int e = t; e < 4096; e += 256) {
      int i16 = e >> 8, c = e & 255;
      y_s[i16 * 260 + c] = ye[((size_t)b * L + idx_s[tile * 16 + i16]) * 256 + c];
    }
    __syncthreads();
    size_t tb = (size_t)b * L * 256 + (size_t)((i0 >> 4) + tile) * 4096;
    for (int e = t; e < 4096; e += 256) {
      int c = e >> 4, k16 = e & 15;
      int sw = ((((k16 >> 2) ^ ((c >> 2) & 3)) << 2) | (k16 & 3));
      yt[tb + c * 16 + sw] = (unsigned short)f2bf(y_s[k16 * 260 + c]);
    }
    __syncthreads();
  }
}

// ---------------- K6: flash MFMA attention ----------------
// grid (3, 64, 8) = (qc, k, b), 192 threads (3 waves, wave w owns 16 queries)
__global__ __launch_bounds__(192, 3) void k_attn(const unsigned short* __restrict__ xk,
                                                 const unsigned short* __restrict__ yt,
                                                 const float* __restrict__ norms,
                                                 const int* __restrict__ sidx,
                                                 float* __restrict__ retb) {
  int qc = blockIdx.x, k = blockIdx.y, b = blockIdx.z;
  __shared__ __align__(16) char lds[40960];  // 2 bufs x (K 4KB + V 16KB)
  int t = threadIdx.x;
  int lane = t & 63;
  int g = lane >> 4, kr = lane & 15;
  int kbase = k * WIN;
  int qr0 = kbase + qc * 48 + (t >> 6) * 16;
  int qrow = qr0 + kr;

  // Q fragments (normalized bf16, un-swizzle blocks)
  s8v qf[2];
#pragma unroll
  for (int s = 0; s < 2; ++s) {
    int blk = (4 * s + g) ^ (qrow & 7);
    qf[s] = *(const s8v*)(xk + ((size_t)b * L + qrow) * 64 + blk * 8);
  }
  float qn = norms[(size_t)b * L + qrow];

  f32x4 acc[16];
#pragma unroll
  for (int nf = 0; nf < 16; ++nf) acc[nf] = (f32x4){0.f, 0.f, 0.f, 0.f};
  float runm = -3e38f, runsum = 0.f;

  auto stage = [&](int c, int buf) {
    char* kb = lds + buf * 20480;
    char* vb = kb + 4096;
    for (int e = t; e < 1280; e += 192) {
      if (e < 256) {
        int key32 = e >> 3;
        if (c == 13 && key32 >= 16) continue;
        int j = c * 32 + key32;
        int r = (j >= 288) ? 2 : (j >= 144) ? 1 : 0;
        int kk = (r == 0) ? k : (r == 1) ? ((k + 63) & 63) : ((k + 1) & 63);
        int phys = kk * WIN + (j - r * 144);
        const char* gp = (const char*)xk + (((size_t)b * L + phys) * 64 + (e & 7) * 8) * 2;
        __builtin_amdgcn_global_load_lds((const __attribute__((address_space(1))) void*)gp,
                                         (__attribute__((address_space(3))) void*)(kb + e * 16),
                                         16, 0, 0);
      } else {
        int u = e - 256;
        int f = u >> 9;
        if (c == 13 && f == 1) continue;
        int j0 = c * 32 + f * 16;
        int r = (j0 >= 288) ? 2 : (j0 >= 144) ? 1 : 0;
        int kk = (r == 0) ? k : (r == 1) ? ((k + 63) & 63) : ((k + 1) & 63);
        int rowbase = kk * WIN + (j0 - r * 144);
        const char* gp = (const char*)yt + ((size_t)b * L + rowbase) * 512 + (size_t)(u & 511) * 16;
        __builtin_amdgcn_global_load_lds((const __attribute__((address_space(1))) void*)gp,
                                         (__attribute__((address_space(3))) void*)(vb + u * 16),
                                         16, 0, 0);
      }
    }
  };

  auto compute = [&](int c, int buf) {
    char* kb = lds + buf * 20480;
    char* vb = kb + 4096;
    int nm = (c == 13) ? 1 : 2;
    // QK^T (swapped): D[key][q]
    f32x4 sa[2];
    sa[0] = (f32x4){0.f, 0.f, 0.f, 0.f};
    sa[1] = (f32x4){0.f, 0.f, 0.f, 0.f};
#pragma unroll
    for (int m = 0; m < 2; ++m)
      if (m < nm) {
        int row32 = m * 16 + kr;
#pragma unroll
        for (int s = 0; s < 2; ++s) {
          int off = row32 * 128 + (((4 * s + g) ^ (row32 & 7)) * 16);
          s8v kf = *(const s8v*)(kb + off);
          sa[m] = __builtin_amdgcn_mfma_f32_16x16x32_bf16(kf, qf[s], sa[m], 0, 0, 0);
        }
      }
    // online softmax (per lane: query kr, keys 16m+4g+r)
    float p[2][4];
    float mx = -3e38f;
#pragma unroll
    for (int m = 0; m < 2; ++m)
#pragma unroll
      for (int r = 0; r < 4; ++r) {
        float v = (m < nm) ? sa[m][r] * qn : -3e38f;
        p[m][r] = v;
        mx = fmaxf(mx, v);
      }
    mx = fmaxf(mx, __shfl_xor(mx, 16));
    mx = fmaxf(mx, __shfl_xor(mx, 32));
    float newm = fmaxf(runm, mx);
    float corr = __expf(runm - newm);
    runm = newm;
    float psum = 0.f;
#pragma unroll
    for (int m = 0; m < 2; ++m)
#pragma unroll
      for (int r = 0; r < 4; ++r) {
        float pv = __expf(p[m][r] - newm);
        p[m][r] = pv;
        psum += pv;
      }
    runsum = runsum * corr + psum;
    if (__any(corr < 1.0f)) {
      float f0 = __shfl(corr, 4 * g + 0);
      float f1 = __shfl(corr, 4 * g + 1);
      float f2 = __shfl(corr, 4 * g + 2);
      float f3 = __shfl(corr, 4 * g + 3);
#pragma unroll
      for (int nf = 0; nf < 16; ++nf) {
        acc[nf][0] *= f0; acc[nf][1] *= f1; acc[nf][2] *= f2; acc[nf][3] *= f3;
      }
    }
    s8v pa;
#pragma unroll
    for (int e2 = 0; e2 < 8; ++e2) pa[e2] = f2bf(p[e2 >> 2][e2 & 3]);
    // PV: B-frags via plain ds_read_b64 from V^T swizzled tiles
#pragma unroll
    for (int nf = 0; nf < 16; ++nf) {
      int cch = nf * 16 + kr;
      int grp = g ^ ((cch >> 2) & 3);
      s4v lo = *(const s4v*)(vb + cch * 32 + grp * 8);
      s4v hi = *(const s4v*)(vb + 8192 + cch * 32 + grp * 8);
      s8v bfv = __builtin_shufflevector(lo, hi, 0, 1, 2, 3, 4, 5, 6, 7);
      acc[nf] = __builtin_amdgcn_mfma_f32_16x16x32_bf16(pa, bfv, acc[nf], 0, 0, 0);
    }
  };

  stage(0, 0);
  __syncthreads();
  for (int c = 0; c < 14; ++c) {
    if (c < 13) stage(c + 1, (c + 1) & 1);
    compute(c, c & 1);
    __syncthreads();
  }

  // epilogue: normalize + scatter to original positions
  runsum += __shfl_xor(runsum, 16);
  runsum += __shfl_xor(runsum, 32);
  float inv = 1.0f / runsum;  // lanes 0..15 hold queries 0..15
  float invr[4];
  int lorig[4];
#pragma unroll
  for (int r = 0; r < 4; ++r) {
    invr[r] = __shfl(inv, 4 * g + r);
    lorig[r] = sidx[b * L + qr0 + 4 * g + r];
  }
#pragma unroll
  for (int nf = 0; nf < 16; ++nf)
#pragma unroll
    for (int r = 0; r < 4; ++r)
      retb[((size_t)b * L + lorig[r]) * 256 + nf * 16 + kr] = acc[nf][r] * invr[r];
}

// ---------------- K7: transpose + residual ----------------
__global__ __launch_bounds__(256) void k_final(const float* __restrict__ in,
                                               const float* __restrict__ retb,
                                               float* __restrict__ out) {
  int lt = blockIdx.x, ct = blockIdx.y, b = blockIdx.z;
  int l0 = lt * 32, c0 = ct * 32;
  __shared__ float t_s[32][33];
  int t = threadIdx.x;
  for (int e = t; e < 1024; e += 256) {
    int i = e >> 5, j = e & 31;
    t_s[i][j] = retb[((size_t)b * L + l0 + i) * 256 + c0 + j];
  }
  __syncthreads();
  for (int e = t; e < 1024; e += 256) {
    int ci = e >> 5, lj = e & 31;
    size_t o = ((size_t)b * CC + c0 + ci) * L + l0 + lj;
    out[o] = in[o] + 0.1f * t_s[lj][ci];
  }
}

extern "C" void kernel_launch(void* const* d_in, const int* in_sizes, int n_in,
                              void* d_out, int out_size, void* d_ws, size_t ws_size,
                              hipStream_t stream) {
  const float* input = (const float*)d_in[0];
  const float* wm = (const float*)d_in[1];
  const float* bm = (const float*)d_in[2];
  const float* wa = (const float*)d_in[3];
  const float* ba = (const float*)d_in[4];
  const float* means = (const float*)d_in[5];
  float* out = (float*)d_out;

  float* ws = (float*)d_ws;
  float* x_embed = ws;                                      // 4,718,592 f
  float* y_embed = ws + 4718592ull;                         // 18,874,368 f (aliased as retb)
  float* retb = y_embed;
  unsigned short* xk = (unsigned short*)(ws + 23592960ull); // 4,718,592 bf16
  unsigned short* yt = (unsigned short*)(ws + 25952256ull); // 18,874,368 bf16
  float* norms = ws + 35389440ull;                          // 73,728 f
  int* buckets = (int*)(ws + 35463168ull);                  // 73,728 i
  int* sidx = buckets + 73728;                              // 73,728 i

  k_conv3<<<dim3(96, 8), 256, 0, stream>>>(input, wm, bm, x_embed);
  k_conv1<<<dim3(144, 4, 8), 256, 0, stream>>>(input, wa, ba, y_embed);
  k_bucket<<<dim3(288, 8), 256, 0, stream>>>(x_embed, means, buckets);
  k_sort<<<dim3(8), 128, 0, stream>>>(buckets, sidx);
  k_gather<<<dim3(144, 8), 256, 0, stream>>>(x_embed, y_embed, sidx, xk, yt, norms);
  k_attn<<<dim3(3, 64, 8), 192, 0, stream>>>(xk, yt, norms, sidx, retb);
  k_final<<<dim3(288, 8, 8), 256, 0, stream>>>(input, retb, out);
}

// Round 4
// 850.136 us; speedup vs baseline: 2.5863x; 1.6848x over previous
//
#include <hip/hip_runtime.h>
#include <math.h>

#define L 9216
#define HH 96
#define WW 96
#define CC 256
#define CR 64
#define NCLUST 128
#define WIN 144
#define NK 64   // L/WIN

typedef float f32x4 __attribute__((ext_vector_type(4)));
typedef short s8v __attribute__((ext_vector_type(8)));
typedef short s4v __attribute__((ext_vector_type(4)));

static __device__ __forceinline__ short f2bf(float x) {
  union { float f; unsigned u; } v; v.f = x;
  unsigned r = (v.u + 0x7FFF + ((v.u >> 16) & 1)) >> 16;
  return (short)r;
}

// ---------------- K1: conv3x3 (pad=1) -> x_embed[b][l][64] ----------------
__global__ __launch_bounds__(256) void k_conv3(const float* __restrict__ in,
                                               const float* __restrict__ wm,
                                               const float* __restrict__ bm,
                                               float* __restrict__ xe) {
  int h = blockIdx.x, b = blockIdx.y;
  __shared__ float in_s[16 * 300];
  __shared__ float w_s[144 * 66];
  int t = threadIdx.x;
  int ocg = t >> 4, wg = t & 15;
  int oc0 = ocg * 4, w0 = wg * 6;
  float acc[4][6];
  for (int j = 0; j < 4; ++j) {
    float bv = bm[oc0 + j];
    for (int i = 0; i < 6; ++i) acc[j][i] = bv;
  }
  const float* inb = in + (size_t)b * CC * L;
  for (int icc = 0; icc < 16; ++icc) {
    int ic0 = icc * 16;
    for (int e = t; e < 16 * 3 * 98; e += 256) {
      int ic = e / 294, rem = e % 294;
      int r = rem / 98, col = rem % 98;
      int gr = h + r - 1, gc = col - 1;
      float v = 0.f;
      if (gr >= 0 && gr < HH && gc >= 0 && gc < WW)
        v = inb[(size_t)(ic0 + ic) * L + gr * WW + gc];
      in_s[ic * 300 + r * 100 + col] = v;
    }
    for (int e = t; e < 9216; e += 256) {
      int oc = e / 144, r = e % 144;
      w_s[r * 66 + oc] = wm[(size_t)oc * 2304 + (size_t)ic0 * 9 + r];
    }
    __syncthreads();
    for (int ic = 0; ic < 16; ++ic) {
      for (int kh = 0; kh < 3; ++kh) {
        float iv[8];
#pragma unroll
        for (int i = 0; i < 8; ++i) iv[i] = in_s[ic * 300 + kh * 100 + w0 + i];
#pragma unroll
        for (int kw = 0; kw < 3; ++kw) {
          float wv[4];
#pragma unroll
          for (int j = 0; j < 4; ++j)
            wv[j] = w_s[(ic * 9 + kh * 3 + kw) * 66 + oc0 + j];
#pragma unroll
          for (int j = 0; j < 4; ++j)
#pragma unroll
            for (int i = 0; i < 6; ++i) acc[j][i] += wv[j] * iv[i + kw];
        }
      }
    }
    __syncthreads();
  }
  for (int i = 0; i < 6; ++i) {
    int l = h * WW + w0 + i;
    float4 o;
    o.x = acc[0][i]; o.y = acc[1][i]; o.z = acc[2][i]; o.w = acc[3][i];
    *(float4*)&xe[((size_t)b * L + l) * CR + oc0] = o;
  }
}

// ---------------- K2: conv1x1 -> y_embed[b][l][256] ----------------
__global__ __launch_bounds__(256) void k_conv1(const float* __restrict__ in,
                                               const float* __restrict__ wa,
                                               const float* __restrict__ ba,
                                               float* __restrict__ ye) {
  int lt = blockIdx.x, ot = blockIdx.y, b = blockIdx.z;
  int l0 = lt * 64, ocb = ot * 64;
  __shared__ float in_s[32 * 64];
  __shared__ float w_s[32 * 66];
  int t = threadIdx.x;
  int ocg = t & 15, pg = t >> 4;
  int oc0 = ocg * 4, px0 = pg * 4;
  float acc[4][4];
  for (int p = 0; p < 4; ++p)
    for (int j = 0; j < 4; ++j) acc[p][j] = ba[ocb + oc0 + j];
  const float* inb = in + (size_t)b * CC * L;
  for (int icc = 0; icc < 8; ++icc) {
    int ic0 = icc * 32;
    for (int e = t; e < 2048; e += 256) {
      int ic = e >> 6, px = e & 63;
      in_s[ic * 64 + px] = inb[(size_t)(ic0 + ic) * L + l0 + px];
    }
    for (int e = t; e < 2048; e += 256) {
      int oc = e >> 5, ic = e & 31;
      w_s[ic * 66 + oc] = wa[(size_t)(ocb + oc) * CC + ic0 + ic];
    }
    __syncthreads();
    for (int ic = 0; ic < 32; ++ic) {
      float w0v = w_s[ic * 66 + oc0 + 0];
      float w1v = w_s[ic * 66 + oc0 + 1];
      float w2v = w_s[ic * 66 + oc0 + 2];
      float w3v = w_s[ic * 66 + oc0 + 3];
      float4 xv = *(float4*)&in_s[ic * 64 + px0];
      acc[0][0] += xv.x * w0v; acc[0][1] += xv.x * w1v; acc[0][2] += xv.x * w2v; acc[0][3] += xv.x * w3v;
      acc[1][0] += xv.y * w0v; acc[1][1] += xv.y * w1v; acc[1][2] += xv.y * w2v; acc[1][3] += xv.y * w3v;
      acc[2][0] += xv.z * w0v; acc[2][1] += xv.z * w1v; acc[2][2] += xv.z * w2v; acc[2][3] += xv.z * w3v;
      acc[3][0] += xv.w * w0v; acc[3][1] += xv.w * w1v; acc[3][2] += xv.w * w2v; acc[3][3] += xv.w * w3v;
    }
    __syncthreads();
  }
  for (int p = 0; p < 4; ++p) {
    float4 o;
    o.x = acc[p][0]; o.y = acc[p][1]; o.z = acc[p][2]; o.w = acc[p][3];
    *(float4*)&ye[((size_t)b * L + l0 + px0 + p) * CC + ocb + oc0] = o;
  }
}

// ---------------- K3: buckets = argmax_c(x . mean_c) ----------------
__global__ __launch_bounds__(256) void k_bucket(const float* __restrict__ xe,
                                                const float* __restrict__ means,
                                                int* __restrict__ buckets) {
  int lt = blockIdx.x, b = blockIdx.y;
  int l0 = lt * 32;
  __shared__ float x_s[32 * 65];
  __shared__ float m_s[128 * 65];
  __shared__ float bv_s[32 * 8];
  __shared__ int bi_s[32 * 8];
  int t = threadIdx.x;
  for (int e = t; e < 2048; e += 256) {
    int px = e >> 6, d = e & 63;
    x_s[px * 65 + d] = xe[((size_t)b * L + l0) * 64 + e];
  }
  for (int e = t; e < 8192; e += 256) {
    int c = e >> 6, d = e & 63;
    m_s[c * 65 + d] = means[e];
  }
  __syncthreads();
  int px = t >> 3, cg = t & 7;
  float best = -1e30f;
  int bidx = 0;
  const float* xr = &x_s[px * 65];
  for (int cc = 0; cc < 16; ++cc) {
    int c = cg + 8 * cc;
    const float* mr = &m_s[c * 65];
    float d = 0.f;
#pragma unroll
    for (int dd = 0; dd < 64; ++dd) d += xr[dd] * mr[dd];
    if (d > best || (d == best && c < bidx)) { best = d; bidx = c; }
  }
  bv_s[px * 8 + cg] = best;
  bi_s[px * 8 + cg] = bidx;
  __syncthreads();
  if (cg == 0) {
    float bb = bv_s[px * 8];
    int bbi = bi_s[px * 8];
    for (int g = 1; g < 8; ++g) {
      float v = bv_s[px * 8 + g];
      int vi = bi_s[px * 8 + g];
      if (v > bb || (v == bb && vi < bbi)) { bb = v; bbi = vi; }
    }
    buckets[b * L + l0 + px] = bbi;
  }
}

// ---------------- K4: parallel stable counting sort ----------------
// 256 threads; thread c owns chunk [c*36, c*36+36). Stability: chunks are in
// index order, within-chunk processing is sequential, cross-chunk offsets come
// from a chunk-ordered prefix scan.
#define SCH 256
#define CHL 36
__global__ __launch_bounds__(256) void k_sort(const int* __restrict__ buckets,
                                              int* __restrict__ sidx) {
  int b = blockIdx.x, t = threadIdx.x;
  __shared__ int keys_s[L];                      // 36 KB
  __shared__ unsigned short cnt_s[SCH][130];     // 65 KB, padded stride
  __shared__ int halfsum0[NCLUST];
  __shared__ int keytotal[NCLUST];
  __shared__ int keybase[NCLUST];
  const int* bk = buckets + b * L;
  for (int i = t; i < L; i += SCH) keys_s[i] = bk[i];
  for (int i = 0; i < 130; ++i) cnt_s[t][i] = 0;
  __syncthreads();
  // phase 1: per-chunk histogram
  {
    int base = t * CHL;
    for (int i = 0; i < CHL; ++i) cnt_s[t][keys_s[base + i]]++;
  }
  __syncthreads();
  // phase 2a: per-key exclusive prefix over chunks, split into 2 halves
  {
    int kkey = t & 127, h = t >> 7;
    int c0 = h * 128;
    int run = 0;
    for (int c = 0; c < 128; ++c) {
      int v = cnt_s[c0 + c][kkey];
      cnt_s[c0 + c][kkey] = (unsigned short)run;
      run += v;
    }
    if (h == 0) halfsum0[kkey] = run;
    else keytotal[kkey] = run;  // second-half total (temp)
  }
  __syncthreads();
  if (t < NCLUST) keytotal[t] += halfsum0[t];
  __syncthreads();
  // phase 2b: exclusive scan of keytotal -> keybase (serial, pipelined reads)
  if (t == 0) {
    int s = 0;
    for (int i = 0; i < NCLUST; ++i) { keybase[i] = s; s += keytotal[i]; }
  }
  __syncthreads();
  // phase 3: emit
  {
    int h = t >> 7;
    int base = t * CHL;
    int* sb = sidx + b * L;
    for (int i = 0; i < CHL; ++i) {
      int kkey = keys_s[base + i];
      int pos = keybase[kkey] + (h ? halfsum0[kkey] : 0) + cnt_s[t][kkey];
      cnt_s[t][kkey]++;
      sb[pos] = base + i;
    }
  }
}

// ---------------- K5: gather + normalize -> xk (bf16 swizzled), yt (bf16 V^T tiles) ----------------
// yt layout per 16-key tile: [c (256)][k16 (16)], with k16-group swizzle:
//   stored slot = c*16 + (((k16>>2) ^ ((c>>2)&3))<<2 | (k16&3))
__global__ __launch_bounds__(256) void k_gather(const float* __restrict__ xe,
                                                const float* __restrict__ ye,
                                                const int* __restrict__ sidx,
                                                unsigned short* __restrict__ xk,
                                                unsigned short* __restrict__ yt,
                                                float* __restrict__ norms) {
  int it = blockIdx.x, b = blockIdx.y;
  int i0 = it * 64;
  __shared__ float x_s[64 * 65];
  __shared__ float y_s[16 * 260];
  __shared__ int idx_s[64];
  __shared__ float scale_s[64];
  int t = threadIdx.x;
  if (t < 64) idx_s[t] = sidx[b * L + i0 + t];
  __syncthreads();
  for (int e = t; e < 4096; e += 256) {
    int i = e >> 6, d = e & 63;
    x_s[i * 65 + d] = xe[((size_t)b * L + idx_s[i]) * 64 + d];
  }
  __syncthreads();
  if (t < 64) {
    float s = 0.f;
    const float* xr = &x_s[t * 65];
#pragma unroll
    for (int d = 0; d < 64; ++d) s += xr[d] * xr[d];
    float n = fmaxf(sqrtf(s), 5e-5f);
    norms[b * L + i0 + t] = n;
    scale_s[t] = 1.0f / n;
  }
  __syncthreads();
  // xk: normalized bf16, 16B blocks XOR-swizzled by (row&7)
  for (int e = t; e < 4096; e += 256) {
    int i = e >> 6, d = e & 63;
    int ig = i0 + i;
    int db = (((d >> 3) ^ (ig & 7)) << 3) | (d & 7);
    xk[((size_t)b * L + ig) * 64 + db] = (unsigned short)f2bf(x_s[i * 65 + d] * scale_s[i]);
  }
  // yt: V^T tiles via LDS transpose
  for (int tile = 0; tile < 4; ++tile) {
    for (int e = t; e < 4096; e += 256) {
      int i16 = e >> 8, c = e & 255;
      y_s[i16 * 260 + c] = ye[((size_t)b * L + idx_s[tile * 16 + i16]) * 256 + c];
    }
    __syncthreads();
    size_t tb = (size_t)b * L * 256 + (size_t)((i0 >> 4) + tile) * 4096;
    for (int e = t; e < 4096; e += 256) {
      int c = e >> 4, k16 = e & 15;
      int sw = ((((k16 >> 2) ^ ((c >> 2) & 3)) << 2) | (k16 & 3));
      yt[tb + c * 16 + sw] = (unsigned short)f2bf(y_s[k16 * 260 + c]);
    }
    __syncthreads();
  }
}

// ---------------- K6: flash MFMA attention ----------------
// grid (3, 64, 8) = (qc, k, b), 192 threads (3 waves, wave w owns 16 queries)
__global__ __launch_bounds__(192, 3) void k_attn(const unsigned short* __restrict__ xk,
                                                 const unsigned short* __restrict__ yt,
                                                 const float* __restrict__ norms,
                                                 const int* __restrict__ sidx,
                                                 float* __restrict__ retb) {
  int qc = blockIdx.x, k = blockIdx.y, b = blockIdx.z;
  __shared__ __align__(16) char lds[40960];  // 2 bufs x (K 4KB + V 16KB)
  int t = threadIdx.x;
  int lane = t & 63;
  int g = lane >> 4, kr = lane & 15;
  int kbase = k * WIN;
  int qr0 = kbase + qc * 48 + (t >> 6) * 16;
  int qrow = qr0 + kr;

  // Q fragments (normalized bf16, un-swizzle blocks)
  s8v qf[2];
#pragma unroll
  for (int s = 0; s < 2; ++s) {
    int blk = (4 * s + g) ^ (qrow & 7);
    qf[s] = *(const s8v*)(xk + ((size_t)b * L + qrow) * 64 + blk * 8);
  }
  float qn = norms[(size_t)b * L + qrow];

  f32x4 acc[16];
#pragma unroll
  for (int nf = 0; nf < 16; ++nf) acc[nf] = (f32x4){0.f, 0.f, 0.f, 0.f};
  float runm = -3e38f, runsum = 0.f;

  auto stage = [&](int c, int buf) {
    char* kb = lds + buf * 20480;
    char* vb = kb + 4096;
    for (int e = t; e < 1280; e += 192) {
      if (e < 256) {
        int key32 = e >> 3;
        if (c == 13 && key32 >= 16) continue;
        int j = c * 32 + key32;
        int r = (j >= 288) ? 2 : (j >= 144) ? 1 : 0;
        int kk = (r == 0) ? k : (r == 1) ? ((k + 63) & 63) : ((k + 1) & 63);
        int phys = kk * WIN + (j - r * 144);
        const char* gp = (const char*)xk + (((size_t)b * L + phys) * 64 + (e & 7) * 8) * 2;
        __builtin_amdgcn_global_load_lds((const __attribute__((address_space(1))) void*)gp,
                                         (__attribute__((address_space(3))) void*)(kb + e * 16),
                                         16, 0, 0);
      } else {
        int u = e - 256;
        int f = u >> 9;
        if (c == 13 && f == 1) continue;
        int j0 = c * 32 + f * 16;
        int r = (j0 >= 288) ? 2 : (j0 >= 144) ? 1 : 0;
        int kk = (r == 0) ? k : (r == 1) ? ((k + 63) & 63) : ((k + 1) & 63);
        int rowbase = kk * WIN + (j0 - r * 144);
        const char* gp = (const char*)yt + ((size_t)b * L + rowbase) * 512 + (size_t)(u & 511) * 16;
        __builtin_amdgcn_global_load_lds((const __attribute__((address_space(1))) void*)gp,
                                         (__attribute__((address_space(3))) void*)(vb + u * 16),
                                         16, 0, 0);
      }
    }
  };

  auto compute = [&](int c, int buf) {
    char* kb = lds + buf * 20480;
    char* vb = kb + 4096;
    int nm = (c == 13) ? 1 : 2;
    // QK^T (swapped): D[key][q]
    f32x4 sa[2];
    sa[0] = (f32x4){0.f, 0.f, 0.f, 0.f};
    sa[1] = (f32x4){0.f, 0.f, 0.f, 0.f};
#pragma unroll
    for (int m = 0; m < 2; ++m)
      if (m < nm) {
        int row32 = m * 16 + kr;
#pragma unroll
        for (int s = 0; s < 2; ++s) {
          int off = row32 * 128 + (((4 * s + g) ^ (row32 & 7)) * 16);
          s8v kf = *(const s8v*)(kb + off);
          sa[m] = __builtin_amdgcn_mfma_f32_16x16x32_bf16(kf, qf[s], sa[m], 0, 0, 0);
        }
      }
    // online softmax (per lane: query kr, keys 16m+4g+r)
    float p[2][4];
    float mx = -3e38f;
#pragma unroll
    for (int m = 0; m < 2; ++m)
#pragma unroll
      for (int r = 0; r < 4; ++r) {
        float v = (m < nm) ? sa[m][r] * qn : -3e38f;
        p[m][r] = v;
        mx = fmaxf(mx, v);
      }
    mx = fmaxf(mx, __shfl_xor(mx, 16));
    mx = fmaxf(mx, __shfl_xor(mx, 32));
    float newm = fmaxf(runm, mx);
    float corr = __expf(runm - newm);
    runm = newm;
    float psum = 0.f;
#pragma unroll
    for (int m = 0; m < 2; ++m)
#pragma unroll
      for (int r = 0; r < 4; ++r) {
        float pv = __expf(p[m][r] - newm);
        p[m][r] = pv;
        psum += pv;
      }
    runsum = runsum * corr + psum;
    if (__any(corr < 1.0f)) {
      float f0 = __shfl(corr, 4 * g + 0);
      float f1 = __shfl(corr, 4 * g + 1);
      float f2 = __shfl(corr, 4 * g + 2);
      float f3 = __shfl(corr, 4 * g + 3);
#pragma unroll
      for (int nf = 0; nf < 16; ++nf) {
        acc[nf][0] *= f0; acc[nf][1] *= f1; acc[nf][2] *= f2; acc[nf][3] *= f3;
      }
    }
    s8v pa;
#pragma unroll
    for (int e2 = 0; e2 < 8; ++e2) pa[e2] = f2bf(p[e2 >> 2][e2 & 3]);
    // PV: B-frags via plain ds_read_b64 from V^T swizzled tiles
#pragma unroll
    for (int nf = 0; nf < 16; ++nf) {
      int cch = nf * 16 + kr;
      int grp = g ^ ((cch >> 2) & 3);
      s4v lo = *(const s4v*)(vb + cch * 32 + grp * 8);
      s4v hi = *(const s4v*)(vb + 8192 + cch * 32 + grp * 8);
      s8v bfv = __builtin_shufflevector(lo, hi, 0, 1, 2, 3, 4, 5, 6, 7);
      acc[nf] = __builtin_amdgcn_mfma_f32_16x16x32_bf16(pa, bfv, acc[nf], 0, 0, 0);
    }
  };

  stage(0, 0);
  __syncthreads();
  for (int c = 0; c < 14; ++c) {
    if (c < 13) stage(c + 1, (c + 1) & 1);
    compute(c, c & 1);
    __syncthreads();
  }

  // epilogue: normalize + scatter to original positions
  runsum += __shfl_xor(runsum, 16);
  runsum += __shfl_xor(runsum, 32);
  float inv = 1.0f / runsum;  // lanes 0..15 hold queries 0..15
  float invr[4];
  int lorig[4];
#pragma unroll
  for (int r = 0; r < 4; ++r) {
    invr[r] = __shfl(inv, 4 * g + r);
    lorig[r] = sidx[b * L + qr0 + 4 * g + r];
  }
#pragma unroll
  for (int nf = 0; nf < 16; ++nf)
#pragma unroll
    for (int r = 0; r < 4; ++r)
      retb[((size_t)b * L + lorig[r]) * 256 + nf * 16 + kr] = acc[nf][r] * invr[r];
}

// ---------------- K7: transpose + residual ----------------
__global__ __launch_bounds__(256) void k_final(const float* __restrict__ in,
                                               const float* __restrict__ retb,
                                               float* __restrict__ out) {
  int lt = blockIdx.x, ct = blockIdx.y, b = blockIdx.z;
  int l0 = lt * 32, c0 = ct * 32;
  __shared__ float t_s[32][33];
  int t = threadIdx.x;
  for (int e = t; e < 1024; e += 256) {
    int i = e >> 5, j = e & 31;
    t_s[i][j] = retb[((size_t)b * L + l0 + i) * 256 + c0 + j];
  }
  __syncthreads();
  for (int e = t; e < 1024; e += 256) {
    int ci = e >> 5, lj = e & 31;
    size_t o = ((size_t)b * CC + c0 + ci) * L + l0 + lj;
    out[o] = in[o] + 0.1f * t_s[lj][ci];
  }
}

extern "C" void kernel_launch(void* const* d_in, const int* in_sizes, int n_in,
                              void* d_out, int out_size, void* d_ws, size_t ws_size,
                              hipStream_t stream) {
  const float* input = (const float*)d_in[0];
  const float* wm = (const float*)d_in[1];
  const float* bm = (const float*)d_in[2];
  const float* wa = (const float*)d_in[3];
  const float* ba = (const float*)d_in[4];
  const float* means = (const float*)d_in[5];
  float* out = (float*)d_out;

  float* ws = (float*)d_ws;
  float* x_embed = ws;                                      // 4,718,592 f
  float* y_embed = ws + 4718592ull;                         // 18,874,368 f (aliased as retb)
  float* retb = y_embed;
  unsigned short* xk = (unsigned short*)(ws + 23592960ull); // 4,718,592 bf16
  unsigned short* yt = (unsigned short*)(ws + 25952256ull); // 18,874,368 bf16
  float* norms = ws + 35389440ull;                          // 73,728 f
  int* buckets = (int*)(ws + 35463168ull);                  // 73,728 i
  int* sidx = buckets + 73728;                              // 73,728 i

  k_conv3<<<dim3(96, 8), 256, 0, stream>>>(input, wm, bm, x_embed);
  k_conv1<<<dim3(144, 4, 8), 256, 0, stream>>>(input, wa, ba, y_embed);
  k_bucket<<<dim3(288, 8), 256, 0, stream>>>(x_embed, means, buckets);
  k_sort<<<dim3(8), 256, 0, stream>>>(buckets, sidx);
  k_gather<<<dim3(144, 8), 256, 0, stream>>>(x_embed, y_embed, sidx, xk, yt, norms);
  k_attn<<<dim3(3, 64, 8), 192, 0, stream>>>(xk, yt, norms, sidx, retb);
  k_final<<<dim3(288, 8, 8), 256, 0, stream>>>(input, retb, out);
}